// Round 2
// baseline (1064.250 us; speedup 1.0000x reference)
//
#include <hip/hip_runtime.h>
#include <stdint.h>

// LSTM decoder: VOCAB=32000, EMBED=512, HIDDEN=1024, B=32, S=48.
//   1. cast W_ih, fc_W, hidden -> bf16; pack W_hh -> per-wave MFMA layout
//   2. gather X[s][b][:] = emb[inputs[b][s]] as bf16
//   3. GEMM1: Xg[1536,4096] = X @ W_ih^T + b_ih + b_hh   (fp32 out)
//   4. ONE persistent kernel (64 WGs, device-scope barrier) runs all 48 steps
//   5. GEMM2: out[b][s][v] = Hall[1..48] @ fc_W^T + fc_b (fp32, scatter)

typedef unsigned short u16;
typedef __attribute__((ext_vector_type(8))) short bf16x8;
typedef __attribute__((ext_vector_type(4))) float floatx4;
struct alignas(8) us4 { u16 x, y, z, w; };

#define BATCH 32
#define SEQ   48
#define EMBED 512
#define HID   1024
#define VOCAB 32000
#define MROWS (SEQ * BATCH)   // 1536
#define NWG   64              // persistent-kernel workgroups

__device__ __forceinline__ u16 f2bf(float f) {
  unsigned u = __float_as_uint(f);
  u += 0x7FFF + ((u >> 16) & 1);   // round-to-nearest-even
  return (u16)(u >> 16);
}

__device__ __forceinline__ floatx4 mfma16(bf16x8 a, bf16x8 b, floatx4 c) {
  return __builtin_amdgcn_mfma_f32_16x16x32_bf16(a, b, c, 0, 0, 0);
}

typedef __attribute__((address_space(1))) unsigned int as1_uint;
typedef __attribute__((address_space(3))) unsigned int as3_uint;
__device__ __forceinline__ void gl_lds16(const void* g, void* l) {
  __builtin_amdgcn_global_load_lds((as1_uint*)g, (as3_uint*)l, 16, 0, 0);
}

__device__ __forceinline__ float sigmoidf_(float x) {
  return 1.0f / (1.0f + __expf(-x));
}

// ---------------- cast fp32 -> bf16, 4 elems/thread ----------------
__global__ void cast_kernel(const float* __restrict__ in, u16* __restrict__ out, int n4) {
  int i = blockIdx.x * blockDim.x + threadIdx.x;
  if (i < n4) {
    float4 v = *(const float4*)(in + (size_t)i * 4);
    us4 o;
    o.x = f2bf(v.x); o.y = f2bf(v.y); o.z = f2bf(v.z); o.w = f2bf(v.w);
    *(us4*)(out + (size_t)i * 4) = o;
  }
}

// ---- pack W_hh[4096][1024] fp32 -> Whhp[(g*4+w)][kc=0..127][rf=0..15][8] bf16 ----
// Whhp chunk (gw,kc,rf) = W_hh[w*1024 + g*16 + rf][kc*8 .. +8]
__global__ void pack_whh_kernel(const float* __restrict__ Whh, u16* __restrict__ out) {
  int t = blockIdx.x * blockDim.x + threadIdx.x;     // 0 .. 4096*1024/8-1 = 524287
  int rf = t & 15;
  int kc = (t >> 4) & 127;
  int gw = t >> 11;                                  // g*4 + w
  int g = gw >> 2, w = gw & 3;
  const float* src = Whh + ((size_t)(w * 1024 + g * 16 + rf)) * HID + kc * 8;
  float4 v0 = *(const float4*)(src);
  float4 v1 = *(const float4*)(src + 4);
  u16 o[8] = {f2bf(v0.x), f2bf(v0.y), f2bf(v0.z), f2bf(v0.w),
              f2bf(v1.x), f2bf(v1.y), f2bf(v1.z), f2bf(v1.w)};
  *(bf16x8*)(out + (size_t)t * 8) = *(bf16x8*)o;
}

// ---------------- embedding gather: X[s*32+b][:] = bf16(emb[idx[b][s]]) --------
__global__ void gather_kernel(const int* __restrict__ idx, const float* __restrict__ emb,
                              u16* __restrict__ X) {
  int bid = blockIdx.x;          // = s*32 + b
  int s = bid >> 5, b = bid & 31;
  int t = idx[b * SEQ + s];
  const float* src = emb + (size_t)t * EMBED;
  u16* dst = X + (size_t)bid * EMBED;
  int e = threadIdx.x * 4;       // 128 threads * 4 = 512
  float4 v = *(const float4*)(src + e);
  us4 o;
  o.x = f2bf(v.x); o.y = f2bf(v.y); o.z = f2bf(v.z); o.w = f2bf(v.w);
  *(us4*)(dst + e) = o;
}

// ---------------- tiled bf16 GEMM: C = A[M,K] @ B[N,K]^T + bias ----------------
// 128x128 tile, BK=64, 4 waves, XOR-swizzled LDS, global_load_lds width-16.
// XCD-aware tile remap: xcd = l%8 gets a contiguous strip of N-tiles, M fastest,
// so all M-blocks sharing a B-tile run on one XCD (B fetched once per XCD).
// out_mode 0: C[m*N + n]   out_mode 1: C[(b*SEQ+s)*N + n], b=m&31, s=m>>5
__global__ __launch_bounds__(256) void gemm_bt_kernel(
    const u16* __restrict__ A, const u16* __restrict__ B,
    const float* __restrict__ bias0, const float* __restrict__ bias1,
    float* __restrict__ C, int M, int N, int K, int out_mode) {
  __shared__ u16 As[128 * 64];
  __shared__ u16 Bs[128 * 64];

  const int tid = threadIdx.x;
  const int wave = tid >> 6, lane = tid & 63;
  const int l3 = lane >> 3, l7 = lane & 7;
  const int q = lane >> 4, rf = lane & 15;

  int tm, tn;
  {
    int l = blockIdx.y * gridDim.x + blockIdx.x;
    int total = gridDim.x * gridDim.y;
    if ((total & 7) == 0) {
      int per = total >> 3;
      int seq = (l & 7) * per + (l >> 3);
      int mt = gridDim.y;
      tm = seq % mt;
      tn = seq / mt;
    } else {
      tn = blockIdx.x; tm = blockIdx.y;
    }
  }
  const int gm0 = tm * 128, gn0 = tn * 128;
  const int wm = (wave & 1) * 64, wn = (wave >> 1) * 64;

  floatx4 acc[4][4];
#pragma unroll
  for (int i = 0; i < 4; ++i)
#pragma unroll
    for (int j = 0; j < 4; ++j) acc[i][j] = (floatx4){0.f, 0.f, 0.f, 0.f};

  for (int k0 = 0; k0 < K; k0 += 64) {
#pragma unroll
    for (int i = 0; i < 4; ++i) {
      int e = wave * 4 + i;
      int r = e * 8 + l3;
      int qd = l7 ^ (r & 7);
      gl_lds16(A + (size_t)(gm0 + r) * K + k0 + qd * 8, (void*)(As + e * 512));
      gl_lds16(B + (size_t)(gn0 + r) * K + k0 + qd * 8, (void*)(Bs + e * 512));
    }
    __syncthreads();

#pragma unroll
    for (int kk = 0; kk < 64; kk += 32) {
      int jc = (kk >> 3) + q;
      bf16x8 af[4], bf[4];
#pragma unroll
      for (int mi = 0; mi < 4; ++mi) {
        int r = wm + mi * 16 + rf;
        af[mi] = *(const bf16x8*)(As + r * 64 + (jc ^ (r & 7)) * 8);
      }
#pragma unroll
      for (int ni = 0; ni < 4; ++ni) {
        int r = wn + ni * 16 + rf;
        bf[ni] = *(const bf16x8*)(Bs + r * 64 + (jc ^ (r & 7)) * 8);
      }
#pragma unroll
      for (int mi = 0; mi < 4; ++mi)
#pragma unroll
        for (int ni = 0; ni < 4; ++ni)
          acc[mi][ni] = mfma16(af[mi], bf[ni], acc[mi][ni]);
    }
    __syncthreads();
  }

#pragma unroll
  for (int ni = 0; ni < 4; ++ni) {
    int n = gn0 + wn + ni * 16 + rf;
    float bv = bias0[n];
    if (bias1) bv += bias1[n];
#pragma unroll
    for (int mi = 0; mi < 4; ++mi) {
#pragma unroll
      for (int r = 0; r < 4; ++r) {
        int m = gm0 + wm + mi * 16 + q * 4 + r;
        float val = acc[mi][ni][r] + bv;
        if (out_mode == 0) {
          C[(size_t)m * N + n] = val;
        } else {
          int b = m & 31, s = m >> 5;
          C[((size_t)b * SEQ + s) * N + n] = val;
        }
      }
    }
  }
}

// ---------------- persistent LSTM: all 48 steps in one launch ----------------
// 64 WGs x 256 thr, guaranteed co-resident (64 << 256 CUs). WG g owns units
// [g*16,(g+1)*16); wave w computes gate w for those units (B rows in Whhp,
// pinned hot in this CU's L1/L2 after step 0). c stays in registers. h goes
// through Hall[s] in global; cross-WG sync = threadfence + release-add +
// acquire-spin on a device-scope counter (the grid.sync pattern).
__global__ __launch_bounds__(256) void lstm_persist_kernel(
    const u16* __restrict__ Whhp,     // [64*4][128][16*8] bf16 packed
    const float* __restrict__ xg,     // [48][32][4096] fp32
    const float* __restrict__ cell,   // [32][1024] fp32 initial c
    u16* __restrict__ Hall,           // [49][32][1024] bf16, slot 0 = h0
    unsigned int* bar) {
  __shared__ u16 hs[32 * HID];        // 64 KB, XOR-swizzled 16B chunks
  __shared__ float gsh[4][32][16];    // 8 KB gate exchange

  const int g = blockIdx.x;
  const int tid = threadIdx.x;
  const int w = tid >> 6, lane = tid & 63;
  const int q = lane >> 4, rf = lane & 15;

  // activation mapping: thread t -> (b0=t>>4, ul=t&15) and (b0+16, ul)
  const int b0 = tid >> 4, ul = tid & 15;
  const int b1 = b0 + 16;
  float c0 = cell[(size_t)b0 * HID + g * 16 + ul];
  float c1 = cell[(size_t)b1 * HID + g * 16 + ul];

  const u16* wbase = Whhp + (size_t)(g * 4 + w) * (128 * 128);
  const float* xgl = xg + w * 1024 + g * 16 + rf;

  for (int s = 0; s < SEQ; ++s) {
    // stage h_s -> LDS (coalesced 16B chunks, XOR-swizzle by row)
    const u16* hsrc = Hall + (size_t)s * (32 * HID);
#pragma unroll
    for (int i = 0; i < 16; ++i) {
      int ci = i * 256 + tid;                 // chunk id 0..4095
      int row = ci >> 7, cj = ci & 127;
      *(bf16x8*)(hs + (size_t)(row * 128 + (cj ^ (row & 7))) * 8) =
          *(const bf16x8*)(hsrc + (size_t)ci * 8);
    }
    __syncthreads();

    // gates = h @ Whh^T : wave w -> gate w, N=16 units, M=32 batches, K=1024
    floatx4 acc0 = {0.f, 0.f, 0.f, 0.f}, acc1 = {0.f, 0.f, 0.f, 0.f};
#pragma unroll 8
    for (int it = 0; it < 32; ++it) {
      int kc = it * 4 + q;                    // 16B k-chunk for this quad
      bf16x8 bfr = *(const bf16x8*)(wbase + (size_t)kc * 128 + rf * 8);
      bf16x8 a0 = *(const bf16x8*)(hs + (size_t)(rf * 128 + (kc ^ (rf & 7))) * 8);
      bf16x8 a1 = *(const bf16x8*)(hs + (size_t)((16 + rf) * 128 + (kc ^ (rf & 7))) * 8);
      acc0 = mfma16(a0, bfr, acc0);
      acc1 = mfma16(a1, bfr, acc1);
    }

    // add input-side gates, exchange via LDS (C-layout: row b=q*4+r, col u=rf)
    const float* xgs = xgl + (size_t)s * (32 * 4096);
#pragma unroll
    for (int r = 0; r < 4; ++r) {
      gsh[w][q * 4 + r][rf]      = acc0[r] + xgs[(size_t)(q * 4 + r) * 4096];
      gsh[w][16 + q * 4 + r][rf] = acc1[r] + xgs[(size_t)(16 + q * 4 + r) * 4096];
    }
    __syncthreads();

    // activations: each thread finishes 2 (b,u) cells; c stays in VGPRs
    u16* hdst = Hall + (size_t)(s + 1) * (32 * HID) + g * 16;
    {
      float i_ = sigmoidf_(gsh[0][b0][ul]);
      float f_ = sigmoidf_(gsh[1][b0][ul]);
      float gg = tanhf(gsh[2][b0][ul]);
      float o_ = sigmoidf_(gsh[3][b0][ul]);
      c0 = f_ * c0 + i_ * gg;
      hdst[(size_t)b0 * HID + ul] = f2bf(o_ * tanhf(c0));
    }
    {
      float i_ = sigmoidf_(gsh[0][b1][ul]);
      float f_ = sigmoidf_(gsh[1][b1][ul]);
      float gg = tanhf(gsh[2][b1][ul]);
      float o_ = sigmoidf_(gsh[3][b1][ul]);
      c1 = f_ * c1 + i_ * gg;
      hdst[(size_t)b1 * HID + ul] = f2bf(o_ * tanhf(c1));
    }

    // device-scope barrier: all WGs must see Hall[s+1] before step s+1
    __threadfence();                          // order my stores (agent scope)
    __syncthreads();                          // all threads fenced
    if (tid == 0) {
      __hip_atomic_fetch_add(bar, 1u, __ATOMIC_RELEASE, __HIP_MEMORY_SCOPE_AGENT);
      unsigned tgt = (unsigned)(s + 1) * NWG;
      while (__hip_atomic_load(bar, __ATOMIC_ACQUIRE, __HIP_MEMORY_SCOPE_AGENT) < tgt)
        __builtin_amdgcn_s_sleep(2);
    }
    __syncthreads();                          // broadcast arrival to the WG
  }
}

extern "C" void kernel_launch(void* const* d_in, const int* in_sizes, int n_in,
                              void* d_out, int out_size, void* d_ws, size_t ws_size,
                              hipStream_t stream) {
  const int*   inputs = (const int*)d_in[0];
  const float* hidden = (const float*)d_in[1];
  const float* cell   = (const float*)d_in[2];
  const float* emb    = (const float*)d_in[3];
  const float* W_ih   = (const float*)d_in[4];
  const float* W_hh   = (const float*)d_in[5];
  const float* b_ih   = (const float*)d_in[6];
  const float* b_hh   = (const float*)d_in[7];
  const float* fc_W   = (const float*)d_in[8];
  const float* fc_b   = (const float*)d_in[9];
  float* out = (float*)d_out;

  char* ws = (char*)d_ws;
  // workspace layout (256B aligned), total ~108.1 MiB
  u16*   Xbf  = (u16*)(ws);                         // 1536*512   bf16 = 1,572,864
  u16*   Wihb = (u16*)(ws + 1572864);               // 4096*512   bf16 = 4,194,304
  u16*   Whhp = (u16*)(ws + 5767168);               // 4096*1024  bf16 = 8,388,608 (packed)
  u16*   fcWb = (u16*)(ws + 14155776);              // 32000*1024 bf16 = 65,536,000
  float* Xg   = (float*)(ws + 79691776);            // 1536*4096  f32  = 25,165,824
  u16*   Hall = (u16*)(ws + 104857600);             // 49*32*1024 bf16 = 3,211,264
  unsigned int* bar = (unsigned int*)(ws + 108068864);

  hipMemsetAsync((void*)bar, 0, sizeof(unsigned int), stream);

  // 1) casts / packs
  cast_kernel<<<(4096 * 512 / 4 + 255) / 256, 256, 0, stream>>>(W_ih, Wihb, 4096 * 512 / 4);
  pack_whh_kernel<<<(4096 * 1024 / 8) / 256, 256, 0, stream>>>(W_hh, Whhp);
  cast_kernel<<<(VOCAB * 1024 / 4 + 255) / 256, 256, 0, stream>>>(fc_W, fcWb, VOCAB * 1024 / 4);
  cast_kernel<<<(BATCH * HID / 4 + 255) / 256, 256, 0, stream>>>(hidden, Hall, BATCH * HID / 4);

  // 2) embedding gather (time-major)
  gather_kernel<<<MROWS, 128, 0, stream>>>(inputs, emb, Xbf);

  // 3) GEMM1: Xg = X @ W_ih^T + b_ih + b_hh
  gemm_bt_kernel<<<dim3(4096 / 128, MROWS / 128), 256, 0, stream>>>(
      Xbf, Wihb, b_ih, b_hh, Xg, MROWS, 4096, EMBED, 0);

  // 4) all 48 recurrent steps, one persistent launch
  lstm_persist_kernel<<<NWG, 256, 0, stream>>>(Whhp, Xg, cell, Hall, bar);

  // 5) GEMM2: logits = Hall[1..48] @ fc_W^T + fc_b, scattered to [B][S][V]
  gemm_bt_kernel<<<dim3(VOCAB / 128, MROWS / 128), 256, 0, stream>>>(
      Hall + (size_t)BATCH * HID, fcWb, fc_b, (const float*)nullptr, out,
      MROWS, VOCAB, HID, 1);
}